// Round 6
// baseline (232.678 us; speedup 1.0000x reference)
//
#include <hip/hip_runtime.h>
#include <hip/hip_bf16.h>

// DeformableConv1D: B=4, Cin=256, Cout=256, L=8192, K=7, stride=1, pad=3, dil=1
// out[b,o,l] = sum_{i,kt} w[o,i,kt] * interp(b, l, i, kt) + bias[o]
// loc[b,l,kt] = l + kt + (offset_conv(x)[b,l,kt] + offset_b[kt])
// interp = wa*x[b,i,x0c] + wb*x[b,i,x1c]  (clamped lerp, reference formula)
//
// Round 6:
//  - loc: 4 channel-group partial kernels (grid 2048, wave=16ch so OW fits
//    sK$) + tiny reduce. No atomics.
//  - main: 512-thread blocks, 256o x 128n -> Wf L2 traffic halved, 16
//    waves/CU occupancy cap. i-chunk order kept (L1-resident gathers).
//  - wt_build: W transpose staged through LDS, both sides coalesced.

#define B_    4
#define CIN   256
#define COUT  256
#define LEN   8192
#define KK    7
#define NTOT  (B_ * LEN)          // 32768
#define QTOT  (CIN * KK)          // 1792
#define LPITCH 232                // LDS row pitch (elems); 464 B = 29 b128-groups

typedef short s16x8 __attribute__((ext_vector_type(8)));
typedef float f32x4 __attribute__((ext_vector_type(4)));

static __device__ __forceinline__ unsigned short f2bf(float f) {
  union { float f; unsigned u; } u; u.f = f;
  unsigned r = u.u + 0x7FFF + ((u.u >> 16) & 1);   // RNE (finite inputs)
  return (unsigned short)(r >> 16);
}

// ---------------------------------------------------------------------------
// Kernel 1: offset-conv partials, 4 channel groups of 64. Block g covers
// 64 l; wave w sums channels [g*64+16w, +16); LDS reduce over the 4 waves;
// Partial[(g*NTOT + n)*7 + k] = group sum. Grid 4*512 = 2048.
// ---------------------------------------------------------------------------
__global__ __launch_bounds__(256) void loc_partial(
    const float* __restrict__ X, const float* __restrict__ OW,
    float* __restrict__ Partial) {
  __shared__ float red[4][64][8];              // 8 KB

  const int t    = threadIdx.x;
  const int lane = t & 63;
  const int w    = t >> 6;
  const int g    = blockIdx.x >> 9;            // 0..3
  const int n0   = (blockIdx.x & 511) << 6;
  const int b    = n0 >> 13;
  const int l    = (n0 & (LEN - 1)) + lane;
  const float* xb = X + ((size_t)b << 21);

  float acc[KK];
#pragma unroll
  for (int k = 0; k < KK; ++k) acc[k] = 0.0f;

#pragma unroll 2
  for (int ii = 0; ii < 16; ++ii) {
    const int i = g * 64 + w * 16 + ii;
    const float* xr = xb + ((size_t)i << 13);
    float xv[KK];
#pragma unroll
    for (int j = 0; j < KK; ++j) {
      int pos = l + j - 3;
      xv[j] = ((unsigned)pos < LEN) ? xr[pos] : 0.0f;
    }
#pragma unroll
    for (int k = 0; k < KK; ++k)
#pragma unroll
      for (int j = 0; j < KK; ++j)
        acc[k] += xv[j] * OW[(k * CIN + i) * KK + j];   // wave-uniform i
  }
#pragma unroll
  for (int k = 0; k < KK; ++k) red[w][lane][k] = acc[k];
  __syncthreads();

  for (int e = t; e < 64 * KK; e += 256) {
    int ll = e / KK;
    int k  = e - ll * KK;
    float s = red[0][ll][k] + red[1][ll][k] + red[2][ll][k] + red[3][ll][k];
    Partial[((size_t)g * NTOT + n0 + ll) * KK + k] = s;
  }
}

// ---------------------------------------------------------------------------
// Kernel 2: Loc[n*7+k] = (l+k) + OB[k] + sum_g Partial
// ---------------------------------------------------------------------------
__global__ __launch_bounds__(256) void loc_reduce(
    const float* __restrict__ Partial, const float* __restrict__ OB,
    float* __restrict__ Loc) {
  int e = blockIdx.x * 256 + threadIdx.x;      // grid 896 -> 229376
  int n = e / KK;
  int k = e - n * KK;
  int l = n & (LEN - 1);
  float s = (float)(l + k) + OB[k];
#pragma unroll
  for (int g = 0; g < 4; ++g) s += Partial[(size_t)g * (NTOT * KK) + e];
  Loc[e] = s;
}

// ---------------------------------------------------------------------------
// Kernel 3: weights -> bf16 A-fragments via LDS (coalesced both sides).
// Block (ot, c): stage W[o=ot*16..+16][i=c*32..+32][s<7] (14 KB), then
// frag f = (ot*8+c)*7 + s, elem lane*8+j = W[ot*16+(lane&15)]
//   [(c*32+(lane>>4)*8+j)*7 + s].  Grid 128.
// ---------------------------------------------------------------------------
__global__ __launch_bounds__(256) void wt_build(
    const float* __restrict__ W, unsigned short* __restrict__ Wf) {
  __shared__ float Wl[16 * 32 * KK];           // 14336 B
  const int t  = threadIdx.x;
  const int ot = blockIdx.x >> 3;
  const int c  = blockIdx.x & 7;

  for (int e = t; e < 16 * 32 * KK; e += 256) {
    int o = e / 224;                           // 224 = 32*7
    int r = e - o * 224;
    Wl[e] = W[(size_t)(ot * 16 + o) * QTOT + c * 224 + r];
  }
  __syncthreads();

  const int lane = t & 63;
  const int sg   = t >> 6;                     // 0..3
  const int ol   = lane & 15;
  const int ig   = lane >> 4;
  for (int s = sg; s < KK; s += 4) {           // sg covers {0,4},{1,5},{2,6},{3}
    s16x8 v;
#pragma unroll
    for (int j = 0; j < 8; ++j)
      v[j] = (short)f2bf(Wl[ol * 224 + (ig * 8 + j) * KK + s]);
    int f = (ot * 8 + c) * KK + s;
    *(s16x8*)(Wf + ((size_t)f << 9) + (lane << 3)) = v;
  }
}

// ---------------------------------------------------------------------------
// Kernel 4: main MFMA GEMM. Block = 256(o) x 128(n), 8 waves, grid 256.
// Wave w: o-tile wo = w&3 (64 o), n-half wn = w>>2 (64 n). 8 i-chunks of 32
// channels x all 7 taps. Stage slots: t -> (nl=t&127, kt=t>>7), t+512 ->
// kt=4+(t>>7) for t<384. Per slot: 32 i x 2 gathers (L1-resident window),
// 4 b128 LDS writes. Then 7 MFMA K-steps.
// ---------------------------------------------------------------------------
__global__ __launch_bounds__(512, 2) void main_kernel(
    const float* __restrict__ X, const unsigned short* __restrict__ Wf,
    const float* __restrict__ Bias, const float* __restrict__ Loc,
    float* __restrict__ Out) {
  __shared__ unsigned short Il[128][LPITCH];   // 59392 B

  const int t    = threadIdx.x;
  const int lane = t & 63;
  const int w    = t >> 6;
  const int wo   = w & 3;
  const int wn   = w >> 2;
  const int n0   = blockIdx.x << 7;            // grid 256
  const int b    = n0 >> 13;
  const float* Xb = X + ((size_t)b << 21);

  const int nlA = t & 127;
  const int ktA = t >> 7;                      // 0..3
  const int ktB = 4 + ktA;                     // 4..7
  const bool hasB = (t < 384);

  int x0a, x1a; float waa, wba;
  {
    float locv = Loc[(size_t)(n0 + nlA) * KK + ktA];
    int x0  = (int)floorf(locv);
    x0a = min(max(x0, 0), LEN - 1);
    x1a = min(max(x0 + 1, 0), LEN - 1);
    waa = (float)x1a - locv;
    wba = locv - (float)x0a;
  }
  int x0b = 0, x1b = 0; float wab = 0.f, wbb = 0.f;
  if (hasB) {
    float locv = Loc[(size_t)(n0 + nlA) * KK + ktB];
    int x0  = (int)floorf(locv);
    x0b = min(max(x0, 0), LEN - 1);
    x1b = min(max(x0 + 1, 0), LEN - 1);
    wab = (float)x1b - locv;
    wbb = locv - (float)x0b;
  }

  f32x4 acc[4][4];
#pragma unroll
  for (int a = 0; a < 4; ++a)
#pragma unroll
    for (int cc = 0; cc < 4; ++cc) acc[a][cc] = (f32x4){0.f, 0.f, 0.f, 0.f};

  const int mrow = lane & 15;
  const int quad = lane >> 4;

  for (int c = 0; c < 8; ++c) {                // i-chunks
    const int i0 = c * 32;
    __syncthreads();                           // prev chunk's readers done

    {                                          // slot A
      s16x8 vv[4];
#pragma unroll
      for (int gq = 0; gq < 4; ++gq) {
#pragma unroll
        for (int m = 0; m < 8; ++m) {
          const float* xr = Xb + ((size_t)(i0 + gq * 8 + m) << 13);
          vv[gq][m] = (short)f2bf(waa * xr[x0a] + wba * xr[x1a]);
        }
      }
#pragma unroll
      for (int gq = 0; gq < 4; ++gq)
        *(s16x8*)&Il[nlA][ktA * 32 + gq * 8] = vv[gq];
    }
    if (hasB) {                                // slot B
      s16x8 vv[4];
#pragma unroll
      for (int gq = 0; gq < 4; ++gq) {
#pragma unroll
        for (int m = 0; m < 8; ++m) {
          const float* xr = Xb + ((size_t)(i0 + gq * 8 + m) << 13);
          vv[gq][m] = (short)f2bf(wab * xr[x0b] + wbb * xr[x1b]);
        }
      }
#pragma unroll
      for (int gq = 0; gq < 4; ++gq)
        *(s16x8*)&Il[nlA][ktB * 32 + gq * 8] = vv[gq];
    }
    __syncthreads();                           // staging visible

#pragma unroll
    for (int s = 0; s < KK; ++s) {
      s16x8 bf[4];
#pragma unroll
      for (int nt = 0; nt < 4; ++nt)
        bf[nt] = *(const s16x8*)&Il[wn * 64 + nt * 16 + mrow][s * 32 + quad * 8];
#pragma unroll
      for (int tt = 0; tt < 4; ++tt) {
        const s16x8 af = *(const s16x8*)(
            Wf + ((size_t)(((wo * 4 + tt) * 8 + c) * KK + s) << 9) + (lane << 3));
        acc[tt][0] = __builtin_amdgcn_mfma_f32_16x16x32_bf16(af, bf[0], acc[tt][0], 0, 0, 0);
        acc[tt][1] = __builtin_amdgcn_mfma_f32_16x16x32_bf16(af, bf[1], acc[tt][1], 0, 0, 0);
        acc[tt][2] = __builtin_amdgcn_mfma_f32_16x16x32_bf16(af, bf[2], acc[tt][2], 0, 0, 0);
        acc[tt][3] = __builtin_amdgcn_mfma_f32_16x16x32_bf16(af, bf[3], acc[tt][3], 0, 0, 0);
      }
    }
  }

  // epilogue: D row m = quad*4+r (o), col = mrow (l)
  const int lbase = (n0 & (LEN - 1)) + wn * 64 + mrow;
#pragma unroll
  for (int tt = 0; tt < 4; ++tt) {
    const int obase = (wo * 4 + tt) * 16 + quad * 4;
#pragma unroll
    for (int r = 0; r < 4; ++r) {
      const int o = obase + r;
      const float bv = Bias[o];
      float* orow = Out + (((size_t)(b * COUT + o)) << 13) + lbase;
#pragma unroll
      for (int nt = 0; nt < 4; ++nt)
        orow[nt * 16] = acc[tt][nt][r] + bv;
    }
  }
}

extern "C" void kernel_launch(void* const* d_in, const int* in_sizes, int n_in,
                              void* d_out, int out_size, void* d_ws, size_t ws_size,
                              hipStream_t stream) {
  const float* X    = (const float*)d_in[0];   // (4,256,8192)
  const float* W    = (const float*)d_in[1];   // (256,256,7)
  const float* Bias = (const float*)d_in[2];   // (256,)
  const float* OW   = (const float*)d_in[3];   // (7,256,7)
  const float* OB   = (const float*)d_in[4];   // (7,)
  float* Out = (float*)d_out;                  // (4,256,8192)

  // ws: Loc (0.92 MB) | Wf (0.92 MB) | Partial (3.67 MB)  = 5.5 MB
  float* Loc = (float*)d_ws;
  unsigned short* Wf = (unsigned short*)(Loc + (size_t)NTOT * KK);
  float* Partial = (float*)(Wf + (size_t)COUT * QTOT);

  loc_partial<<<4 * 512, 256, 0, stream>>>(X, OW, Partial);
  loc_reduce<<<NTOT * KK / 256, 256, 0, stream>>>(Partial, OB, Loc);
  wt_build<<<128, 256, 0, stream>>>(W, Wf);
  main_kernel<<<NTOT / 128, 512, 0, stream>>>(X, Wf, Bias, Loc, Out);
}

// Round 7
// 226.722 us; speedup vs baseline: 1.0263x; 1.0263x over previous
//
#include <hip/hip_runtime.h>
#include <hip/hip_bf16.h>

// DeformableConv1D: B=4, Cin=256, Cout=256, L=8192, K=7, stride=1, pad=3, dil=1
// out[b,o,l] = sum_{i,kt} w[o,i,kt] * interp(b, l, i, kt) + bias[o]
// loc[b,l,kt] = l + kt + (offset_conv(x)[b,l,kt] + offset_b[kt])
// interp = wa*x[b,i,x0c] + wb*x[b,i,x1c]  (clamped lerp, reference formula)
//
// Round 7:
//  - main: 512-thread blocks (8 waves), o 256 x n 64, grid 512 -> 2 blocks/CU
//    but 16 waves/CU (2x round 5). Each wave: 32 o x 64 n (32 acc VGPRs).
//    Staging: 448 slots (64 n x 7 kt), one slot/thread, 32 elems/chunk.
//  - loc/wt kernels: unchanged from round 6 (not in top-5).

#define B_    4
#define CIN   256
#define COUT  256
#define LEN   8192
#define KK    7
#define NTOT  (B_ * LEN)          // 32768
#define QTOT  (CIN * KK)          // 1792
#define LPITCH 232                // LDS row pitch (elems); 464 B

typedef short s16x8 __attribute__((ext_vector_type(8)));
typedef float f32x4 __attribute__((ext_vector_type(4)));

static __device__ __forceinline__ unsigned short f2bf(float f) {
  union { float f; unsigned u; } u; u.f = f;
  unsigned r = u.u + 0x7FFF + ((u.u >> 16) & 1);   // RNE (finite inputs)
  return (unsigned short)(r >> 16);
}

// ---------------------------------------------------------------------------
// Kernel 1: offset-conv partials, 4 channel groups of 64. Block g covers
// 64 l; wave w sums channels [g*64+16w, +16); LDS reduce over the 4 waves;
// Partial[(g*NTOT + n)*7 + k] = group sum. Grid 4*512 = 2048.
// ---------------------------------------------------------------------------
__global__ __launch_bounds__(256) void loc_partial(
    const float* __restrict__ X, const float* __restrict__ OW,
    float* __restrict__ Partial) {
  __shared__ float red[4][64][8];              // 8 KB

  const int t    = threadIdx.x;
  const int lane = t & 63;
  const int w    = t >> 6;
  const int g    = blockIdx.x >> 9;            // 0..3
  const int n0   = (blockIdx.x & 511) << 6;
  const int b    = n0 >> 13;
  const int l    = (n0 & (LEN - 1)) + lane;
  const float* xb = X + ((size_t)b << 21);

  float acc[KK];
#pragma unroll
  for (int k = 0; k < KK; ++k) acc[k] = 0.0f;

#pragma unroll 2
  for (int ii = 0; ii < 16; ++ii) {
    const int i = g * 64 + w * 16 + ii;
    const float* xr = xb + ((size_t)i << 13);
    float xv[KK];
#pragma unroll
    for (int j = 0; j < KK; ++j) {
      int pos = l + j - 3;
      xv[j] = ((unsigned)pos < LEN) ? xr[pos] : 0.0f;
    }
#pragma unroll
    for (int k = 0; k < KK; ++k)
#pragma unroll
      for (int j = 0; j < KK; ++j)
        acc[k] += xv[j] * OW[(k * CIN + i) * KK + j];   // wave-uniform i
  }
#pragma unroll
  for (int k = 0; k < KK; ++k) red[w][lane][k] = acc[k];
  __syncthreads();

  for (int e = t; e < 64 * KK; e += 256) {
    int ll = e / KK;
    int k  = e - ll * KK;
    float s = red[0][ll][k] + red[1][ll][k] + red[2][ll][k] + red[3][ll][k];
    Partial[((size_t)g * NTOT + n0 + ll) * KK + k] = s;
  }
}

// ---------------------------------------------------------------------------
// Kernel 2: Loc[n*7+k] = (l+k) + OB[k] + sum_g Partial
// ---------------------------------------------------------------------------
__global__ __launch_bounds__(256) void loc_reduce(
    const float* __restrict__ Partial, const float* __restrict__ OB,
    float* __restrict__ Loc) {
  int e = blockIdx.x * 256 + threadIdx.x;      // grid 896 -> 229376
  int n = e / KK;
  int k = e - n * KK;
  int l = n & (LEN - 1);
  float s = (float)(l + k) + OB[k];
#pragma unroll
  for (int g = 0; g < 4; ++g) s += Partial[(size_t)g * (NTOT * KK) + e];
  Loc[e] = s;
}

// ---------------------------------------------------------------------------
// Kernel 3: weights -> bf16 A-fragments via LDS (coalesced both sides).
// frag f = (ot*8+c)*7 + s, elem lane*8+j = W[ot*16+(lane&15)]
//   [(c*32+(lane>>4)*8+j)*7 + s].  Grid 128.
// ---------------------------------------------------------------------------
__global__ __launch_bounds__(256) void wt_build(
    const float* __restrict__ W, unsigned short* __restrict__ Wf) {
  __shared__ float Wl[16 * 32 * KK];           // 14336 B
  const int t  = threadIdx.x;
  const int ot = blockIdx.x >> 3;
  const int c  = blockIdx.x & 7;

  for (int e = t; e < 16 * 32 * KK; e += 256) {
    int o = e / 224;                           // 224 = 32*7
    int r = e - o * 224;
    Wl[e] = W[(size_t)(ot * 16 + o) * QTOT + c * 224 + r];
  }
  __syncthreads();

  const int lane = t & 63;
  const int sg   = t >> 6;                     // 0..3
  const int ol   = lane & 15;
  const int ig   = lane >> 4;
  for (int s = sg; s < KK; s += 4) {
    s16x8 v;
#pragma unroll
    for (int j = 0; j < 8; ++j)
      v[j] = (short)f2bf(Wl[ol * 224 + (ig * 8 + j) * KK + s]);
    int f = (ot * 8 + c) * KK + s;
    *(s16x8*)(Wf + ((size_t)f << 9) + (lane << 3)) = v;
  }
}

// ---------------------------------------------------------------------------
// Kernel 4: main MFMA GEMM. Block = 512 threads (8 waves), 256 o x 64 n,
// grid 512 (2 blocks/CU, 16 waves/CU). Wave w: o in [32w, 32w+32) as 2
// o-tiles (tt<2), 4 n-tiles. 8 i-chunks of 32 channels x 7 taps. Staging:
// thread t<448 owns slot (n = t&63, kt = t>>6): 32 elems/chunk, 64 gathers
// (L1-resident window), 4 b128 LDS writes. Then 7 MFMA K-steps/chunk.
// ---------------------------------------------------------------------------
__global__ __launch_bounds__(512, 4) void main_kernel(
    const float* __restrict__ X, const unsigned short* __restrict__ Wf,
    const float* __restrict__ Bias, const float* __restrict__ Loc,
    float* __restrict__ Out) {
  __shared__ unsigned short Il[64][LPITCH];    // 29696 B

  const int t    = threadIdx.x;
  const int lane = t & 63;
  const int w    = t >> 6;                     // 0..7
  const int n0   = blockIdx.x << 6;            // grid 512
  const int b    = n0 >> 13;
  const float* Xb = X + ((size_t)b << 21);

  const bool stager = (t < 448);
  const int nl = t & 63;
  const int kt = t >> 6;                       // 0..6 when stager

  int x0s = 0, x1s = 0; float wa = 0.f, wb = 0.f;
  if (stager) {
    float locv = Loc[(size_t)(n0 + nl) * KK + kt];
    int x0  = (int)floorf(locv);
    x0s = min(max(x0, 0), LEN - 1);
    x1s = min(max(x0 + 1, 0), LEN - 1);
    wa = (float)x1s - locv;
    wb = locv - (float)x0s;
  }

  f32x4 acc[2][4];
#pragma unroll
  for (int a = 0; a < 2; ++a)
#pragma unroll
    for (int cc = 0; cc < 4; ++cc) acc[a][cc] = (f32x4){0.f, 0.f, 0.f, 0.f};

  const int mrow = lane & 15;
  const int quad = lane >> 4;

  for (int c = 0; c < 8; ++c) {                // i-chunks
    const int i0 = c * 32;
    __syncthreads();                           // prev chunk's readers done

    if (stager) {
      s16x8 vv[4];
#pragma unroll
      for (int gq = 0; gq < 4; ++gq) {
        float fa[8], fb[8];
#pragma unroll
        for (int m = 0; m < 8; ++m) {
          const float* xq = Xb + ((size_t)(i0 + gq * 8 + m) << 13);
          fa[m] = xq[x0s];
          fb[m] = xq[x1s];
        }
#pragma unroll
        for (int m = 0; m < 8; ++m)
          vv[gq][m] = (short)f2bf(wa * fa[m] + wb * fb[m]);
      }
#pragma unroll
      for (int gq = 0; gq < 4; ++gq)
        *(s16x8*)&Il[nl][kt * 32 + gq * 8] = vv[gq];
    }
    __syncthreads();                           // staging visible

#pragma unroll
    for (int s = 0; s < KK; ++s) {
      s16x8 bf[4];
#pragma unroll
      for (int nt = 0; nt < 4; ++nt)
        bf[nt] = *(const s16x8*)&Il[nt * 16 + mrow][s * 32 + quad * 8];
#pragma unroll
      for (int tt = 0; tt < 2; ++tt) {
        const int ot = w * 2 + tt;
        const s16x8 af = *(const s16x8*)(
            Wf + ((size_t)((ot * 8 + c) * KK + s) << 9) + (lane << 3));
        acc[tt][0] = __builtin_amdgcn_mfma_f32_16x16x32_bf16(af, bf[0], acc[tt][0], 0, 0, 0);
        acc[tt][1] = __builtin_amdgcn_mfma_f32_16x16x32_bf16(af, bf[1], acc[tt][1], 0, 0, 0);
        acc[tt][2] = __builtin_amdgcn_mfma_f32_16x16x32_bf16(af, bf[2], acc[tt][2], 0, 0, 0);
        acc[tt][3] = __builtin_amdgcn_mfma_f32_16x16x32_bf16(af, bf[3], acc[tt][3], 0, 0, 0);
      }
    }
  }

  // epilogue: D row m = quad*4+r (o), col = mrow (l)
  const int lbase = (n0 & (LEN - 1)) + mrow;
#pragma unroll
  for (int tt = 0; tt < 2; ++tt) {
    const int obase = (w * 2 + tt) * 16 + quad * 4;
#pragma unroll
    for (int r = 0; r < 4; ++r) {
      const int o = obase + r;
      const float bv = Bias[o];
      float* orow = Out + (((size_t)(b * COUT + o)) << 13) + lbase;
#pragma unroll
      for (int nt = 0; nt < 4; ++nt)
        orow[nt * 16] = acc[tt][nt][r] + bv;
    }
  }
}

extern "C" void kernel_launch(void* const* d_in, const int* in_sizes, int n_in,
                              void* d_out, int out_size, void* d_ws, size_t ws_size,
                              hipStream_t stream) {
  const float* X    = (const float*)d_in[0];   // (4,256,8192)
  const float* W    = (const float*)d_in[1];   // (256,256,7)
  const float* Bias = (const float*)d_in[2];   // (256,)
  const float* OW   = (const float*)d_in[3];   // (7,256,7)
  const float* OB   = (const float*)d_in[4];   // (7,)
  float* Out = (float*)d_out;                  // (4,256,8192)

  // ws: Loc (0.92 MB) | Wf (0.92 MB) | Partial (3.67 MB)  = 5.5 MB
  float* Loc = (float*)d_ws;
  unsigned short* Wf = (unsigned short*)(Loc + (size_t)NTOT * KK);
  float* Partial = (float*)(Wf + (size_t)COUT * QTOT);

  loc_partial<<<4 * 512, 256, 0, stream>>>(X, OW, Partial);
  loc_reduce<<<NTOT * KK / 256, 256, 0, stream>>>(Partial, OB, Loc);
  wt_build<<<128, 256, 0, stream>>>(W, Wf);
  main_kernel<<<NTOT / 64, 512, 0, stream>>>(X, Wf, Bias, Loc, Out);
}

// Round 8
// 211.769 us; speedup vs baseline: 1.0987x; 1.0706x over previous
//
#include <hip/hip_runtime.h>
#include <hip/hip_bf16.h>

// DeformableConv1D: B=4, Cin=256, Cout=256, L=8192, K=7, stride=1, pad=3, dil=1
// out[b,o,l] = sum_{i,kt} w[o,i,kt] * interp(b, l, i, kt) + bias[o]
// loc[b,l,kt] = l + kt + (offset_conv(x)[b,l,kt] + offset_b[kt])
// interp = wa*x[b,i,x0c] + wb*x[b,i,x1c]  (clamped lerp, reference formula)
//
// Round 8:
//  - loc_partial: readfirstlane(w) -> OW indices wave-uniform -> s_loads
//    (round 7's 78 us was per-lane vector loads of OW).
//  - main: paired gather (one addr + offset:4, clamp via 2 cndmasks) and
//    double-buffered LDS: prefetch chunk c+1 (two 16-ch halves) while MFMA
//    consumes chunk c; 1 barrier/chunk.

#define B_    4
#define CIN   256
#define COUT  256
#define LEN   8192
#define KK    7
#define NTOT  (B_ * LEN)          // 32768
#define QTOT  (CIN * KK)          // 1792
#define LPITCH 232                // LDS row pitch (elems); 464 B

typedef short s16x8 __attribute__((ext_vector_type(8)));
typedef float f32x4 __attribute__((ext_vector_type(4)));

static __device__ __forceinline__ unsigned short f2bf(float f) {
  union { float f; unsigned u; } u; u.f = f;
  unsigned r = u.u + 0x7FFF + ((u.u >> 16) & 1);   // RNE (finite inputs)
  return (unsigned short)(r >> 16);
}

// ---------------------------------------------------------------------------
// Kernel 1: offset-conv partials, 4 channel groups of 64. Block g covers
// 64 l; wave w sums channels [g*64+16w, +16); LDS reduce over the 4 waves.
// wu = readfirstlane(w) makes OW indices uniform -> s_loads.
// ---------------------------------------------------------------------------
__global__ __launch_bounds__(256) void loc_partial(
    const float* __restrict__ X, const float* __restrict__ OW,
    float* __restrict__ Partial) {
  __shared__ float red[4][64][8];              // 8 KB

  const int t    = threadIdx.x;
  const int lane = t & 63;
  const int wu   = __builtin_amdgcn_readfirstlane(t >> 6);   // wave-uniform
  const int g    = blockIdx.x >> 9;            // 0..3
  const int n0   = (blockIdx.x & 511) << 6;
  const int b    = n0 >> 13;
  const int l    = (n0 & (LEN - 1)) + lane;
  const float* xb = X + ((size_t)b << 21);

  float acc[KK];
#pragma unroll
  for (int k = 0; k < KK; ++k) acc[k] = 0.0f;

#pragma unroll 2
  for (int ii = 0; ii < 16; ++ii) {
    const int i = g * 64 + wu * 16 + ii;       // uniform
    const float* xr = xb + ((size_t)i << 13);
    float xv[KK];
#pragma unroll
    for (int j = 0; j < KK; ++j) {
      int pos = l + j - 3;
      xv[j] = ((unsigned)pos < LEN) ? xr[pos] : 0.0f;
    }
#pragma unroll
    for (int k = 0; k < KK; ++k)
#pragma unroll
      for (int j = 0; j < KK; ++j)
        acc[k] += xv[j] * OW[(k * CIN + i) * KK + j];   // uniform -> s_load
  }
#pragma unroll
  for (int k = 0; k < KK; ++k) red[wu][lane][k] = acc[k];
  __syncthreads();

  for (int e = t; e < 64 * KK; e += 256) {
    int ll = e / KK;
    int k  = e - ll * KK;
    float s = red[0][ll][k] + red[1][ll][k] + red[2][ll][k] + red[3][ll][k];
    Partial[((size_t)g * NTOT + n0 + ll) * KK + k] = s;
  }
}

// ---------------------------------------------------------------------------
// Kernel 2: Loc[n*7+k] = (l+k) + OB[k] + sum_g Partial
// ---------------------------------------------------------------------------
__global__ __launch_bounds__(256) void loc_reduce(
    const float* __restrict__ Partial, const float* __restrict__ OB,
    float* __restrict__ Loc) {
  int e = blockIdx.x * 256 + threadIdx.x;      // grid 896 -> 229376
  int n = e / KK;
  int k = e - n * KK;
  int l = n & (LEN - 1);
  float s = (float)(l + k) + OB[k];
#pragma unroll
  for (int g = 0; g < 4; ++g) s += Partial[(size_t)g * (NTOT * KK) + e];
  Loc[e] = s;
}

// ---------------------------------------------------------------------------
// Kernel 3: weights -> bf16 A-fragments via LDS (coalesced both sides).
// frag f = (ot*8+c)*7 + s, elem lane*8+j = W[ot*16+(lane&15)]
//   [(c*32+(lane>>4)*8+j)*7 + s].  Grid 128.
// ---------------------------------------------------------------------------
__global__ __launch_bounds__(256) void wt_build(
    const float* __restrict__ W, unsigned short* __restrict__ Wf) {
  __shared__ float Wl[16 * 32 * KK];           // 14336 B
  const int t  = threadIdx.x;
  const int ot = blockIdx.x >> 3;
  const int c  = blockIdx.x & 7;

  for (int e = t; e < 16 * 32 * KK; e += 256) {
    int o = e / 224;                           // 224 = 32*7
    int r = e - o * 224;
    Wl[e] = W[(size_t)(ot * 16 + o) * QTOT + c * 224 + r];
  }
  __syncthreads();

  const int lane = t & 63;
  const int sg   = t >> 6;                     // 0..3
  const int ol   = lane & 15;
  const int ig   = lane >> 4;
  for (int s = sg; s < KK; s += 4) {
    s16x8 v;
#pragma unroll
    for (int j = 0; j < 8; ++j)
      v[j] = (short)f2bf(Wl[ol * 224 + (ig * 8 + j) * KK + s]);
    int f = (ot * 8 + c) * KK + s;
    *(s16x8*)(Wf + ((size_t)f << 9) + (lane << 3)) = v;
  }
}

// ---------------------------------------------------------------------------
// Kernel 4: main MFMA GEMM. Block = 512 threads (8 waves), 256 o x 64 n,
// grid 512. Double-buffered LDS; per i-chunk (32 ch x 7 taps): prefetch
// gathers of chunk c+1 overlap MFMA on chunk c; 1 barrier/chunk.
// Paired loads: p = clamp(x0,0,L-2); fa = hi?f1:f0, fb = lo?f0:f1.
// ---------------------------------------------------------------------------
__global__ __launch_bounds__(512, 4) void main_kernel(
    const float* __restrict__ X, const unsigned short* __restrict__ Wf,
    const float* __restrict__ Bias, const float* __restrict__ Loc,
    float* __restrict__ Out) {
  __shared__ unsigned short Il[2][64][LPITCH];   // 59392 B

  const int t    = threadIdx.x;
  const int lane = t & 63;
  const int w    = t >> 6;                     // 0..7
  const int n0   = blockIdx.x << 6;            // grid 512
  const int b    = n0 >> 13;
  const float* Xb = X + ((size_t)b << 21);

  const bool stager = (t < 448);
  const int nl = t & 63;
  const int kt = t >> 6;                       // 0..6 when stager

  int p0 = 0; float wa = 0.f, wb = 0.f; bool hi = false, lo = false;
  if (stager) {
    float locv = Loc[(size_t)(n0 + nl) * KK + kt];
    int x0  = (int)floorf(locv);
    int x0c = min(max(x0, 0), LEN - 1);
    int x1c = min(max(x0 + 1, 0), LEN - 1);
    wa = (float)x1c - locv;
    wb = locv - (float)x0c;
    p0 = min(max(x0, 0), LEN - 2);
    hi = (x0 >= LEN - 1);                      // fa = f1 (both ends = x[L-1])
    lo = (x0 < 0);                             // fb = f0 (both ends = x[0])
  }
  const float* xp = Xb + p0;                   // per-channel: xp + (ch<<13)

  f32x4 acc[2][4];
#pragma unroll
  for (int a = 0; a < 2; ++a)
#pragma unroll
    for (int cc = 0; cc < 4; ++cc) acc[a][cc] = (f32x4){0.f, 0.f, 0.f, 0.f};

  const int mrow = lane & 15;
  const int quad = lane >> 4;

  float f0[16], f1[16];                        // prefetch half (16 ch)

#define GATHER_HALF(i0h)                                        \
  if (stager) {                                                 \
    _Pragma("unroll")                                           \
    for (int m = 0; m < 16; ++m) {                              \
      const float* xr = xp + ((size_t)((i0h) + m) << 13);       \
      f0[m] = xr[0];                                            \
      f1[m] = xr[1];                                            \
    }                                                           \
  }

#define CVT_STORE(buf, i0rel)                                   \
  if (stager) {                                                 \
    s16x8 vv[2];                                                \
    _Pragma("unroll")                                           \
    for (int m = 0; m < 16; ++m) {                              \
      float fa = hi ? f1[m] : f0[m];                            \
      float fb = lo ? f0[m] : f1[m];                            \
      vv[m >> 3][m & 7] = (short)f2bf(wa * fa + wb * fb);       \
    }                                                           \
    *(s16x8*)&Il[buf][nl][kt * 32 + (i0rel)]     = vv[0];       \
    *(s16x8*)&Il[buf][nl][kt * 32 + (i0rel) + 8] = vv[1];       \
  }

  // prologue: stage chunk 0 into buf 0
  GATHER_HALF(0)
  CVT_STORE(0, 0)
  GATHER_HALF(16)
  CVT_STORE(0, 16)
  __syncthreads();

  for (int c = 0; c < 8; ++c) {                // i-chunks
    const int cur = c & 1;

    // issue prefetch loads for chunk c+1, half 0 (stay in flight over MFMA)
    if (c < 7) { GATHER_HALF((c + 1) * 32) }

    // consume chunk c: 7 K-steps
#pragma unroll
    for (int s = 0; s < KK; ++s) {
      s16x8 bf[4];
#pragma unroll
      for (int nt = 0; nt < 4; ++nt)
        bf[nt] = *(const s16x8*)&Il[cur][nt * 16 + mrow][s * 32 + quad * 8];
#pragma unroll
      for (int tt = 0; tt < 2; ++tt) {
        const int ot = w * 2 + tt;
        const s16x8 af = *(const s16x8*)(
            Wf + ((size_t)((ot * 8 + c) * KK + s) << 9) + (lane << 3));
        acc[tt][0] = __builtin_amdgcn_mfma_f32_16x16x32_bf16(af, bf[0], acc[tt][0], 0, 0, 0);
        acc[tt][1] = __builtin_amdgcn_mfma_f32_16x16x32_bf16(af, bf[1], acc[tt][1], 0, 0, 0);
        acc[tt][2] = __builtin_amdgcn_mfma_f32_16x16x32_bf16(af, bf[2], acc[tt][2], 0, 0, 0);
        acc[tt][3] = __builtin_amdgcn_mfma_f32_16x16x32_bf16(af, bf[3], acc[tt][3], 0, 0, 0);
      }
    }

    if (c < 7) {
      const int nxt = 1 - cur;
      CVT_STORE(nxt, 0)                        // store half 0 of chunk c+1
      GATHER_HALF((c + 1) * 32 + 16)           // gather half 1
      CVT_STORE(nxt, 16)
      __syncthreads();                         // chunk c+1 visible
    }
  }
#undef GATHER_HALF
#undef CVT_STORE

  // epilogue: D row m = quad*4+r (o), col = mrow (l)
  const int lbase = (n0 & (LEN - 1)) + mrow;
#pragma unroll
  for (int tt = 0; tt < 2; ++tt) {
    const int obase = (w * 2 + tt) * 16 + quad * 4;
#pragma unroll
    for (int r = 0; r < 4; ++r) {
      const int o = obase + r;
      const float bv = Bias[o];
      float* orow = Out + (((size_t)(b * COUT + o)) << 13) + lbase;
#pragma unroll
      for (int nt = 0; nt < 4; ++nt)
        orow[nt * 16] = acc[tt][nt][r] + bv;
    }
  }
}

extern "C" void kernel_launch(void* const* d_in, const int* in_sizes, int n_in,
                              void* d_out, int out_size, void* d_ws, size_t ws_size,
                              hipStream_t stream) {
  const float* X    = (const float*)d_in[0];   // (4,256,8192)
  const float* W    = (const float*)d_in[1];   // (256,256,7)
  const float* Bias = (const float*)d_in[2];   // (256,)
  const float* OW   = (const float*)d_in[3];   // (7,256,7)
  const float* OB   = (const float*)d_in[4];   // (7,)
  float* Out = (float*)d_out;                  // (4,256,8192)

  // ws: Loc (0.92 MB) | Wf (0.92 MB) | Partial (3.67 MB)  = 5.5 MB
  float* Loc = (float*)d_ws;
  unsigned short* Wf = (unsigned short*)(Loc + (size_t)NTOT * KK);
  float* Partial = (float*)(Wf + (size_t)COUT * QTOT);

  loc_partial<<<4 * 512, 256, 0, stream>>>(X, OW, Partial);
  loc_reduce<<<NTOT * KK / 256, 256, 0, stream>>>(Partial, OB, Loc);
  wt_build<<<128, 256, 0, stream>>>(W, Wf);
  main_kernel<<<NTOT / 64, 512, 0, stream>>>(X, Wf, Bias, Loc, Out);
}

// Round 10
// 168.769 us; speedup vs baseline: 1.3787x; 1.2548x over previous
//
#include <hip/hip_runtime.h>
#include <hip/hip_bf16.h>

// DeformableConv1D: B=4, Cin=256, Cout=256, L=8192, K=7, stride=1, pad=3, dil=1
// out[b,o,l] = sum_{i,kt} w[o,i,kt] * interp(b, l, i, kt) + bias[o]
// loc[b,l,kt] = l + kt + (offset_conv(x)[b,l,kt] + offset_b[kt])
// interp = wa*x[b,i,x0c] + wb*x[b,i,x1c]
//
// Round 10 (= round 9 + compile fix: pack bf16 pair via f2bf, no bit_cast
// of __hip_bfloat162):
//  - loc_partial: 4 l-values per thread -> 4x FMA per OW s_load.
//  - main: af (Wf) fragments loaded into registers BEFORE the gathers each
//    chunk (sched_barrier pins order) -> MFMA phase never drains the gather
//    queue. Gathers in 8-ch quarters interleaved between K-steps.

#define B_    4
#define CIN   256
#define COUT  256
#define LEN   8192
#define KK    7
#define NTOT  (B_ * LEN)          // 32768 = 1<<15
#define QTOT  (CIN * KK)          // 1792
#define LPITCH 232                // LDS row pitch (elems); 464 B

typedef short s16x8 __attribute__((ext_vector_type(8)));
typedef int   s32x4 __attribute__((ext_vector_type(4)));
typedef float f32x4 __attribute__((ext_vector_type(4)));

static __device__ __forceinline__ unsigned f2bf(float f) {
  union { float f; unsigned u; } u; u.f = f;
  unsigned r = u.u + 0x7FFF + ((u.u >> 16) & 1);   // RNE (finite inputs)
  return r >> 16;
}

// ---------------------------------------------------------------------------
// Kernel 1: offset-conv partials. Grid 512: cg = bid>>7 (4 ch-groups of 64),
// 256 l per block. Wave w: 16 channels; thread: 4 l (lane + 64r).
// OW loads uniform (s_load), amortized over 4 l. LDS reduce over waves.
// Partial[(cg*7+k)][n] layout (coalesced).
// ---------------------------------------------------------------------------
__global__ __launch_bounds__(256) void loc_partial(
    const float* __restrict__ X, const float* __restrict__ OW,
    float* __restrict__ Partial) {
  __shared__ float red[4][256][KK];            // 28672 B

  const int t    = threadIdx.x;
  const int lane = t & 63;
  const int wu   = __builtin_amdgcn_readfirstlane(t >> 6);
  const int cg   = blockIdx.x >> 7;            // 0..3
  const int nb   = (blockIdx.x & 127) << 8;    // 256 n per block
  const int b    = nb >> 13;
  const int l0   = nb & (LEN - 1);

  float acc[KK][4];
#pragma unroll
  for (int k = 0; k < KK; ++k)
#pragma unroll
    for (int r = 0; r < 4; ++r) acc[k][r] = 0.0f;

#pragma unroll 2
  for (int ii = 0; ii < 16; ++ii) {
    const int i = cg * 64 + wu * 16 + ii;      // uniform
    float owv[49];
#pragma unroll
    for (int k = 0; k < KK; ++k)
#pragma unroll
      for (int j = 0; j < KK; ++j)
        owv[k * 7 + j] = OW[(k * CIN + i) * KK + j];   // uniform -> s_load

    const float* xr = X + ((size_t)(b * CIN + i) << 13);
#pragma unroll
    for (int r = 0; r < 4; ++r) {
      const int lr = l0 + lane + 64 * r;
      float xv[KK];
#pragma unroll
      for (int j = 0; j < KK; ++j) {
        int pos = lr + j - 3;
        xv[j] = ((unsigned)pos < LEN) ? xr[pos] : 0.0f;
      }
#pragma unroll
      for (int k = 0; k < KK; ++k)
#pragma unroll
        for (int j = 0; j < KK; ++j)
          acc[k][r] += xv[j] * owv[k * 7 + j];
    }
  }

#pragma unroll
  for (int k = 0; k < KK; ++k)
#pragma unroll
    for (int r = 0; r < 4; ++r) red[wu][lane + 64 * r][k] = acc[k][r];
  __syncthreads();

#pragma unroll
  for (int k = 0; k < KK; ++k) {
    float s = red[0][t][k] + red[1][t][k] + red[2][t][k] + red[3][t][k];
    Partial[((size_t)(cg * 7 + k) << 15) + nb + t] = s;   // coalesced
  }
}

// ---------------------------------------------------------------------------
// Kernel 2: Loc[k][n] = (l+k) + OB[k] + sum_cg Partial[cg*7+k][n]
// ---------------------------------------------------------------------------
__global__ __launch_bounds__(256) void loc_reduce(
    const float* __restrict__ Partial, const float* __restrict__ OB,
    float* __restrict__ Loc) {
  int n = blockIdx.x * 256 + threadIdx.x;      // grid 128 -> 32768
  int l = n & (LEN - 1);
#pragma unroll
  for (int k = 0; k < KK; ++k) {
    float s = (float)(l + k) + OB[k];
#pragma unroll
    for (int cg = 0; cg < 4; ++cg)
      s += Partial[((size_t)(cg * 7 + k) << 15) + n];
    Loc[((size_t)k << 15) + n] = s;
  }
}

// ---------------------------------------------------------------------------
// Kernel 3: weights -> bf16 A-fragments via LDS (coalesced both sides).
// frag f = (ot*8+c)*7 + s, elem lane*8+j = W[ot*16+(lane&15)]
//   [(c*32+(lane>>4)*8+j)*7 + s].  Grid 128.
// ---------------------------------------------------------------------------
__global__ __launch_bounds__(256) void wt_build(
    const float* __restrict__ W, unsigned short* __restrict__ Wf) {
  __shared__ float Wl[16 * 32 * KK];           // 14336 B
  const int t  = threadIdx.x;
  const int ot = blockIdx.x >> 3;
  const int c  = blockIdx.x & 7;

  for (int e = t; e < 16 * 32 * KK; e += 256) {
    int o = e / 224;
    int r = e - o * 224;
    Wl[e] = W[(size_t)(ot * 16 + o) * QTOT + c * 224 + r];
  }
  __syncthreads();

  const int lane = t & 63;
  const int sg   = t >> 6;
  const int ol   = lane & 15;
  const int ig   = lane >> 4;
  for (int s = sg; s < KK; s += 4) {
    s16x8 v;
#pragma unroll
    for (int j = 0; j < 8; ++j)
      v[j] = (short)f2bf(Wl[ol * 224 + (ig * 8 + j) * KK + s]);
    int f = (ot * 8 + c) * KK + s;
    *(s16x8*)(Wf + ((size_t)f << 9) + (lane << 3)) = v;
  }
}

// ---------------------------------------------------------------------------
// Kernel 4: main MFMA GEMM. Block = 512 threads (8 waves), 256 o x 64 n,
// grid 512. Per chunk: af frags -> registers FIRST, then gathers for c+1
// in 8-channel quarters interleaved between MFMA K-steps; MFMA phase has
// no dependence on the gather queue. Double-buffered Il, 1 barrier/chunk.
// ---------------------------------------------------------------------------
__global__ __launch_bounds__(512, 4) void main_kernel(
    const float* __restrict__ X, const unsigned short* __restrict__ Wf,
    const float* __restrict__ Bias, const float* __restrict__ Loc,
    float* __restrict__ Out) {
  __shared__ unsigned short Il[2][64][LPITCH];   // 59392 B

  const int t    = threadIdx.x;
  const int lane = t & 63;
  const int w    = t >> 6;                     // 0..7
  const int n0   = blockIdx.x << 6;            // grid 512
  const int b    = n0 >> 13;
  const float* Xb = X + ((size_t)b << 21);

  const bool stager = (t < 448);
  const int nl = t & 63;
  const int kt = t >> 6;                       // 0..6 when stager

  float c0 = 0.f, c1 = 0.f;
  const float* xp = Xb;
  if (stager) {
    float locv = Loc[((size_t)kt << 15) + n0 + nl];
    int x0  = (int)floorf(locv);
    int x0c = min(max(x0, 0), LEN - 1);
    int x1c = min(max(x0 + 1, 0), LEN - 1);
    float wa = (float)x1c - locv;
    float wb = locv - (float)x0c;
    bool hi = (x0 >= LEN - 1);
    bool lo = (x0 < 0);
    c0 = (hi ? 0.f : wa) + (lo ? wb : 0.f);   // coeff of x[p0]
    c1 = (hi ? wa : 0.f) + (lo ? 0.f : wb);   // coeff of x[p0+1]
    xp = Xb + min(max(x0, 0), LEN - 2);
  }

  f32x4 acc[2][4];
#pragma unroll
  for (int a = 0; a < 2; ++a)
#pragma unroll
    for (int cc = 0; cc < 4; ++cc) acc[a][cc] = (f32x4){0.f, 0.f, 0.f, 0.f};

  const int mrow = lane & 15;
  const int quad = lane >> 4;

  float f0[8], f1[8];

#define GATHER_Q(chunk, q)                                        \
  if (stager) {                                                   \
    _Pragma("unroll")                                             \
    for (int m = 0; m < 8; ++m) {                                 \
      const float* xr = xp + ((size_t)((chunk) * 32 + (q) * 8 + m) << 13); \
      f0[m] = xr[0];                                              \
      f1[m] = xr[1];                                              \
    }                                                             \
  }

#define CVT_Q(dst, q)                                             \
  if (stager) {                                                   \
    s32x4 vv;                                                     \
    _Pragma("unroll")                                             \
    for (int m = 0; m < 4; ++m) {                                 \
      float a = c0 * f0[2 * m]     + c1 * f1[2 * m];              \
      float d = c0 * f0[2 * m + 1] + c1 * f1[2 * m + 1];          \
      vv[m] = (int)(f2bf(a) | (f2bf(d) << 16));                   \
    }                                                             \
    *(s32x4*)((dst) + nl * LPITCH + kt * 32 + (q) * 8) = vv;      \
  }

#define AFL(ttv, sv)                                              \
  (*(const s16x8*)(Wf + ((size_t)(((w * 2 + (ttv)) * 8 + c) * KK + (sv)) << 9) + (lane << 3)))

#define MSTEP(sv, a0, a1) {                                                        \
    const s16x8 b0 = *(const s16x8*)(Icur + (mrow)      * LPITCH + (sv) * 32 + quad * 8); \
    const s16x8 b1 = *(const s16x8*)(Icur + (16 + mrow) * LPITCH + (sv) * 32 + quad * 8); \
    acc[0][0] = __builtin_amdgcn_mfma_f32_16x16x32_bf16(a0, b0, acc[0][0], 0, 0, 0); \
    acc[1][0] = __builtin_amdgcn_mfma_f32_16x16x32_bf16(a1, b0, acc[1][0], 0, 0, 0); \
    acc[0][1] = __builtin_amdgcn_mfma_f32_16x16x32_bf16(a0, b1, acc[0][1], 0, 0, 0); \
    acc[1][1] = __builtin_amdgcn_mfma_f32_16x16x32_bf16(a1, b1, acc[1][1], 0, 0, 0); \
    const s16x8 b2 = *(const s16x8*)(Icur + (32 + mrow) * LPITCH + (sv) * 32 + quad * 8); \
    const s16x8 b3 = *(const s16x8*)(Icur + (48 + mrow) * LPITCH + (sv) * 32 + quad * 8); \
    acc[0][2] = __builtin_amdgcn_mfma_f32_16x16x32_bf16(a0, b2, acc[0][2], 0, 0, 0); \
    acc[1][2] = __builtin_amdgcn_mfma_f32_16x16x32_bf16(a1, b2, acc[1][2], 0, 0, 0); \
    acc[0][3] = __builtin_amdgcn_mfma_f32_16x16x32_bf16(a0, b3, acc[0][3], 0, 0, 0); \
    acc[1][3] = __builtin_amdgcn_mfma_f32_16x16x32_bf16(a1, b3, acc[1][3], 0, 0, 0); \
  }

  // prologue: stage chunk 0 into Il[0]
  {
    unsigned short* I0 = &Il[0][0][0];
    GATHER_Q(0, 0) CVT_Q(I0, 0)
    GATHER_Q(0, 1) CVT_Q(I0, 1)
    GATHER_Q(0, 2) CVT_Q(I0, 2)
    GATHER_Q(0, 3) CVT_Q(I0, 3)
  }
  __syncthreads();

  for (int c = 0; c < 8; ++c) {
    const int cur = c & 1;
    const unsigned short* Icur = &Il[cur][0][0];
    unsigned short*       Inxt = &Il[cur ^ 1][0][0];

    // af fragments for s=0..3 FIRST (before any gather this chunk)
    s16x8 afA[2][4];
#pragma unroll
    for (int tt = 0; tt < 2; ++tt)
#pragma unroll
      for (int s = 0; s < 4; ++s) afA[tt][s] = AFL(tt, s);
    __builtin_amdgcn_sched_barrier(0);

    if (c < 7) { GATHER_Q(c + 1, 0) }
    MSTEP(0, afA[0][0], afA[1][0])
    if (c < 7) { CVT_Q(Inxt, 0) GATHER_Q(c + 1, 1) }
    MSTEP(1, afA[0][1], afA[1][1])

    // af fragments for s=4..6 (before gather quarters 2,3)
    s16x8 afB[2][3];
#pragma unroll
    for (int tt = 0; tt < 2; ++tt)
#pragma unroll
      for (int s = 0; s < 3; ++s) afB[tt][s] = AFL(tt, 4 + s);
    __builtin_amdgcn_sched_barrier(0);

    if (c < 7) { CVT_Q(Inxt, 1) GATHER_Q(c + 1, 2) }
    MSTEP(2, afA[0][2], afA[1][2])
    if (c < 7) { CVT_Q(Inxt, 2) GATHER_Q(c + 1, 3) }
    MSTEP(3, afA[0][3], afA[1][3])
    if (c < 7) { CVT_Q(Inxt, 3) }
    MSTEP(4, afB[0][0], afB[1][0])
    MSTEP(5, afB[0][1], afB[1][1])
    MSTEP(6, afB[0][2], afB[1][2])
    if (c < 7) __syncthreads();
  }
#undef GATHER_Q
#undef CVT_Q
#undef AFL
#undef MSTEP

  // epilogue: D row m = quad*4+r (o), col = mrow (l)
  const int lbase = (n0 & (LEN - 1)) + mrow;
#pragma unroll
  for (int tt = 0; tt < 2; ++tt) {
    const int obase = (w * 2 + tt) * 16 + quad * 4;
#pragma unroll
    for (int r = 0; r < 4; ++r) {
      const int o = obase + r;
      const float bv = Bias[o];
      float* orow = Out + (((size_t)(b * COUT + o)) << 13) + lbase;
#pragma unroll
      for (int nt = 0; nt < 4; ++nt)
        orow[nt * 16] = acc[tt][nt][r] + bv;
    }
  }
}

extern "C" void kernel_launch(void* const* d_in, const int* in_sizes, int n_in,
                              void* d_out, int out_size, void* d_ws, size_t ws_size,
                              hipStream_t stream) {
  const float* X    = (const float*)d_in[0];   // (4,256,8192)
  const float* W    = (const float*)d_in[1];   // (256,256,7)
  const float* Bias = (const float*)d_in[2];   // (256,)
  const float* OW   = (const float*)d_in[3];   // (7,256,7)
  const float* OB   = (const float*)d_in[4];   // (7,)
  float* Out = (float*)d_out;                  // (4,256,8192)

  // ws: Loc (0.92 MB) | Wf (0.92 MB) | Partial (3.5 MB)  = 5.4 MB
  float* Loc = (float*)d_ws;
  unsigned short* Wf = (unsigned short*)(Loc + (size_t)NTOT * KK);
  float* Partial = (float*)(Wf + (size_t)COUT * QTOT);

  loc_partial<<<4 * 128, 256, 0, stream>>>(X, OW, Partial);
  loc_reduce<<<NTOT / 256, 256, 0, stream>>>(Partial, OB, Loc);
  wt_build<<<128, 256, 0, stream>>>(W, Wf);
  main_kernel<<<NTOT / 64, 512, 0, stream>>>(X, Wf, Bias, Loc, Out);
}